// Round 4
// baseline (314.458 us; speedup 1.0000x reference)
//
#include <hip/hip_runtime.h>
#include <hip/hip_fp16.h>
#include <stdint.h>
#include <stddef.h>

#define FIN 256
#define NH  64
#define CAP 64     // max degree: E/N=16 avg Poisson, P(deg>64) ~ 1e-19
#define NBKT 196   // ceil(50000/256) dst buckets of 256 nodes
#define BCAP 4608  // bucket region capacity: mean 4082, sd 64, +8 sigma
#define LBUF 32    // LDS staging records per bucket
#define LSTR 33    // padded LDS stride (odd -> banks spread across buckets)
#define ROUND 4096 // edges staged per block-synchronous round
#define EPB 4096   // edges per block in pass 1 (= 1 round -> 588 blocks)
#define C2K 128    // conv2: blocks per (view, src-half)

typedef unsigned int uint;
typedef __attribute__((ext_vector_type(8))) short bf16x8;  // MFMA A/B frag (4 VGPRs)
typedef __attribute__((ext_vector_type(4))) float f32x4;   // MFMA C/D frag

union ABfrag { uint u[4]; bf16x8 v; };

// pack two fp32 -> bf16 pair (RNE), low = first element
__device__ __forceinline__ uint pack_bf16x2(float a, float b) {
  uint ua = __float_as_uint(a);
  uint ub = __float_as_uint(b);
  uint ra = (ua + 0x7FFFu + ((ua >> 16) & 1u)) >> 16;
  uint rb = (ub + 0x7FFFu + ((ub >> 16) & 1u)) & 0xFFFF0000u;
  return ra | rb;
}

__device__ __forceinline__ float rec_w(uint r) {
  return __half2float(__ushort_as_half((unsigned short)(r >> 16)));
}

// ---------------- W1 -> MFMA B-frag swizzle + zero bucket counters ----------
// wsw[v][ks(8)][nt(4)][lane(64)][4 uints]; elem j = W1[ks*32+(lane>>4)*8+j][nt*16+(lane&15)]
__global__ __launch_bounds__(256) void k_wprep(
    const float* __restrict__ W10, const float* __restrict__ W11, const float* __restrict__ W12,
    uint* __restrict__ wsw, int* __restrict__ bcnt) {
  int v = blockIdx.x;
  const float* __restrict__ W = v == 0 ? W10 : (v == 1 ? W11 : W12);
  uint4* __restrict__ o = (uint4*)(wsw + v * 8192);
  for (int t = threadIdx.x; t < 2048; t += 256) {
    int lane = t & 63;
    int nt = (t >> 6) & 3;
    int ks = t >> 8;
    int kb = ks * 32 + (lane >> 4) * 8;
    int col = nt * 16 + (lane & 15);
    uint4 r;
    r.x = pack_bf16x2(W[(kb + 0) * NH + col], W[(kb + 1) * NH + col]);
    r.y = pack_bf16x2(W[(kb + 2) * NH + col], W[(kb + 3) * NH + col]);
    r.z = pack_bf16x2(W[(kb + 4) * NH + col], W[(kb + 5) * NH + col]);
    r.w = pack_bf16x2(W[(kb + 6) * NH + col], W[(kb + 7) * NH + col]);
    o[t] = r;
  }
  if (threadIdx.x < NBKT) bcnt[v * NBKT + threadIdx.x] = 0;
}

// ---------------- pass 1: bucket edges by dst>>8 via LDS staging ------------
// stage: 1 edge/thread; flush: PER-THREAD (parallel contended atomics --
// wave-serial flush with returning atomics was a 200us regression in R9)
__global__ __launch_bounds__(256) void k_p1(
    const int* __restrict__ ei0, const int* __restrict__ ei1, const int* __restrict__ ei2,
    const float* __restrict__ ew0, const float* __restrict__ ew1, const float* __restrict__ ew2,
    int* __restrict__ bcnt, uint2* __restrict__ bbuf, int E) {
  int v = blockIdx.y;
  const int*   ei = v == 0 ? ei0 : (v == 1 ? ei1 : ei2);
  const float* ew = v == 0 ? ew0 : (v == 1 ? ew1 : ew2);
  int* __restrict__ bc = bcnt + v * NBKT;
  uint2* __restrict__ bb = bbuf + (size_t)v * NBKT * BCAP;
  __shared__ uint2 buf[NBKT * LSTR];   // 51.7 KB -> 3 blocks/CU
  __shared__ int ticket[NBKT];
  int tid = threadIdx.x;
  int base = blockIdx.x * EPB;
  int end = min(base + EPB, E);
  for (int rbase = base; rbase < end; rbase += ROUND) {
    for (int b = tid; b < NBKT; b += 256) ticket[b] = 0;
    __syncthreads();
    for (int i = 0; i < ROUND; i += 256) {
      int e = rbase + i + tid;
      if (e < end) {
        int s = ei[e];
        int d = ei[E + e];
        float w = ew[e];
        int bkt = d >> 8;
        uint2 rec;
        rec.x = (uint)s | ((uint)(d & 255) << 16);
        rec.y = __float_as_uint(w);
        int t = atomicAdd(&ticket[bkt], 1);
        if (t < LBUF) {
          buf[bkt * LSTR + t] = rec;
        } else {
          int gp = atomicAdd(&bc[bkt], 1);
          if (gp < BCAP) bb[(size_t)bkt * BCAP + gp] = rec;
        }
      }
    }
    __syncthreads();
    // flush: one thread per bucket -> all global atomics issue concurrently
    for (int b = tid; b < NBKT; b += 256) {
      int c = min(ticket[b], LBUF);
      if (c > 0) {
        int gbase = atomicAdd(&bc[b], c);
        for (int j = 0; j < c; j++) {
          int gp = gbase + j;
          if (gp < BCAP) bb[(size_t)b * BCAP + gp] = buf[b * LSTR + j];
        }
      }
    }
    __syncthreads();
  }
}

// ---------------- pass 2: bucket -> segmented CSR rows + cnt/cntA + dinv ----
// Row layout: [src<H entries (cA)][src>=H entries][zero pads to 8-mult].
// Total deg/dpad/pad content identical to before -> conv1 unchanged.
// conv2 uses cntA to address its src-half segment (LDS-staged g gather).
__global__ __launch_bounds__(256) void k_p2(
    const int* __restrict__ bcnt, const uint2* __restrict__ bbuf,
    int* __restrict__ cnt, int* __restrict__ cntA, uint* __restrict__ csr,
    float* __restrict__ dinv1, float* __restrict__ dinv2, int N, int H) {
  int bkt = blockIdx.x;
  int v = blockIdx.y;
  int tid = threadIdx.x;
  __shared__ int cA[256];
  __shared__ int cB[256];
  __shared__ int cB2[256];
  __shared__ float lsum[256];
  cA[tid] = 0; cB[tid] = 0; cB2[tid] = 0; lsum[tid] = 0.f;
  __syncthreads();
  int m = min(bcnt[v * NBKT + bkt], BCAP);
  const uint2* __restrict__ bb = bbuf + ((size_t)v * NBKT + bkt) * BCAP;
  int nb = bkt << 8;
  int vN = v * N;
  // pass A: place src<H entries from the front; count src>=H; full weight sum
  for (int i = tid; i < m; i += 256) {
    uint2 rec = bb[i];
    int src = rec.x & 0xFFFFu;
    int dl = (rec.x >> 16) & 0xFFu;
    float w = __uint_as_float(rec.y);
    atomicAdd(&lsum[dl], w);
    uint r4 = (uint)src | ((uint)__half_as_ushort(__float2half_rn(w)) << 16);
    if (src < H) {
      int pos = atomicAdd(&cA[dl], 1);
      if (pos < CAP) csr[((size_t)(vN + nb + dl)) * CAP + pos] = r4;
    } else {
      atomicAdd(&cB[dl], 1);
    }
  }
  __syncthreads();
  // pass B: place src>=H entries right after segment A (bucket re-read is L2-hot)
  for (int i = tid; i < m; i += 256) {
    uint2 rec = bb[i];
    int src = rec.x & 0xFFFFu;
    if (src >= H) {
      int dl = (rec.x >> 16) & 0xFFu;
      float w = __uint_as_float(rec.y);
      uint r4 = (uint)src | ((uint)__half_as_ushort(__float2half_rn(w)) << 16);
      int pos = min(cA[dl], CAP) + atomicAdd(&cB2[dl], 1);
      if (pos < CAP) csr[((size_t)(vN + nb + dl)) * CAP + pos] = r4;
    }
  }
  __syncthreads();
  int node = nb + tid;
  if (node < N) {
    int a = min(cA[tid], CAP);
    int deg = min(cA[tid] + cB[tid], CAP);
    int dpad = min((deg + 7) & ~7, CAP);
    uint* __restrict__ row = csr + (size_t)(vN + node) * CAP;
    for (int i = deg; i < dpad; i++) row[i] = 0u;  // src=0, w=+0 (inert in conv1)
    cnt[vN + node] = deg;
    cntA[vN + node] = a;
    dinv1[vN + node] = rsqrtf(1.0f + lsum[tid]);
    dinv2[vN + node] = rsqrtf((float)(deg + 1));
  }
}

// ---------------- GEMM1 via MFMA, 3 branches fused (x read once) ------------
__global__ __launch_bounds__(256) void k_gemm1m(
    const float* __restrict__ x, const uint* __restrict__ wsw,
    const float* __restrict__ dinv1, uint* __restrict__ xwb, int N) {
  __shared__ float sc_all[4 * 16 * 64];  // 16 KB epilogue scratch (per-wave 4 KB)
  int wave = threadIdx.x >> 6, lane = threadIdx.x & 63;
  int n0 = blockIdx.x * 64 + wave * 16;
  int m = lane & 15, kq = lane >> 4;  // A: node m, k-group kq
  int arow = min(n0 + m, N - 1);
  const float* __restrict__ xr = x + (size_t)arow * FIN + kq * 8;
  ABfrag af[8];
#pragma unroll
  for (int ks = 0; ks < 8; ks++) {
    float4 a0 = *(const float4*)(xr + ks * 32);
    float4 a1 = *(const float4*)(xr + ks * 32 + 4);
    af[ks].u[0] = pack_bf16x2(a0.x, a0.y);
    af[ks].u[1] = pack_bf16x2(a0.z, a0.w);
    af[ks].u[2] = pack_bf16x2(a1.x, a1.y);
    af[ks].u[3] = pack_bf16x2(a1.z, a1.w);
  }
  float* sc = &sc_all[wave * 1024];  // 16x64 fp32 per wave
  int row2 = lane >> 2, cg = lane & 3;
  int node = n0 + row2;
#pragma unroll
  for (int v = 0; v < 3; v++) {
    int vN = v * N;
    f32x4 acc[4];
#pragma unroll
    for (int nt = 0; nt < 4; nt++) acc[nt] = (f32x4){0.f, 0.f, 0.f, 0.f};
    const uint* __restrict__ wv = wsw + v * 8192;
#pragma unroll
    for (int ks = 0; ks < 8; ks++) {
#pragma unroll
      for (int nt = 0; nt < 4; nt++) {
        ABfrag b;
        *(uint4*)b.u = *(const uint4*)&wv[(ks * 4 + nt) * 256 + lane * 4];
        acc[nt] = __builtin_amdgcn_mfma_f32_16x16x32_bf16(af[ks].v, b.v, acc[nt], 0, 0, 0);
      }
    }
    __syncthreads();  // epilogue scratch reuse boundary (prev v's reads done)
#pragma unroll
    for (int reg = 0; reg < 4; reg++) {
      int row = kq * 4 + reg;            // C/D: row=(lane>>4)*4+reg, col=lane&15
      float d1 = dinv1[vN + min(n0 + row, N - 1)];
#pragma unroll
      for (int nt = 0; nt < 4; nt++)
        sc[row * 64 + nt * 16 + m] = acc[nt][reg] * d1;
    }
    __syncthreads();
    const float4* sr = (const float4*)&sc[row2 * 64 + cg * 16];
    float4 c0 = sr[0], c1 = sr[1], c2 = sr[2], c3 = sr[3];
    uint4 o0, o1;
    o0.x = pack_bf16x2(c0.x, c0.y); o0.y = pack_bf16x2(c0.z, c0.w);
    o0.z = pack_bf16x2(c1.x, c1.y); o0.w = pack_bf16x2(c1.z, c1.w);
    o1.x = pack_bf16x2(c2.x, c2.y); o1.y = pack_bf16x2(c2.z, c2.w);
    o1.z = pack_bf16x2(c3.x, c3.y); o1.w = pack_bf16x2(c3.z, c3.w);
    if (node < N) {
      uint4* __restrict__ dst = (uint4*)(xwb + ((size_t)vN + node) * 32 + cg * 8);
      dst[0] = o0;
      dst[1] = o1;
    }
  }
}

// ---------------- conv1 pull: 16 lanes/node, full-line gathers --------------
// R12 analysis: FETCH ~130MB is per-XCD compulsory duplication (8 XCDs x 3
// views x 0.86 coverage x 50k x 128B). Rate ~55 G line-req/s with VALU 34%,
// occ 46% -> limited by per-CU outstanding-miss capacity x miss latency
// (~31 outstanding/CU). Row-entry reorder (src segments) does not change
// this kernel's behavior: same slot count, pads still inert.
#define EDG(r, a)                                                  \
  {                                                                \
    uint2 pp = *(const uint2*)(xv + (((r) & 0xFFFFu) << 7) + so);  \
    float ww = rec_w(r);                                           \
    a.x = fmaf(ww, __uint_as_float(pp.x << 16), a.x);              \
    a.y = fmaf(ww, __uint_as_float(pp.x & 0xFFFF0000u), a.y);      \
    a.z = fmaf(ww, __uint_as_float(pp.y << 16), a.z);              \
    a.w = fmaf(ww, __uint_as_float(pp.y & 0xFFFF0000u), a.w);      \
  }

__global__ __launch_bounds__(256) void k_conv1(
    const uint* __restrict__ xwb, const uint* __restrict__ csr,
    const int* __restrict__ cnt,
    const float* __restrict__ dinv1, const float* __restrict__ dinv2,
    const float* __restrict__ b10, const float* __restrict__ b11, const float* __restrict__ b12,
    const float* __restrict__ W20, const float* __restrict__ W21, const float* __restrict__ W22,
    float* __restrict__ outf, float* __restrict__ g, int N) {
  int gt = blockIdx.x * 256 + threadIdx.x;
  int l = gt & 15;
  int n = gt >> 4;
  if (n >= N) return;
  int so = l << 3;  // lane's byte offset (8B) within the 128B xwb row
  const float* b1s[3] = {b10, b11, b12};
  const float* W2s[3] = {W20, W21, W22};
  int c0 = cnt[n], c1 = cnt[N + n], c2 = cnt[2 * N + n];  // hoisted
  float4 fs = {0.f, 0.f, 0.f, 0.f};
#pragma unroll
  for (int v = 0; v < 3; v++) {
    int vN = v * N;
    int nv = vN + n;
    const char* __restrict__ xv = (const char*)xwb + (size_t)vN * 128;  // SGPR base
    const uint* __restrict__ row = csr + (size_t)nv * CAP;  // 256B-aligned
    int deg = v == 0 ? c0 : (v == 1 ? c1 : c2);
    int dpad = (deg + 7) & ~7;
    float4 aA = {0.f, 0.f, 0.f, 0.f}, aB = {0.f, 0.f, 0.f, 0.f};
    for (int i = 0; i < dpad; i += 8) {
      uint4 ra = *(const uint4*)(row + i);      // broadcast within 16-lane group
      uint4 rb = *(const uint4*)(row + i + 4);
      EDG(ra.x, aA); EDG(ra.y, aB);
      EDG(ra.z, aA); EDG(ra.w, aB);
      EDG(rb.x, aA); EDG(rb.y, aB);
      EDG(rb.z, aA); EDG(rb.w, aB);
    }
    uint2 ps = *(const uint2*)(xv + (((uint)n) << 7) + so);  // self loop
    float4 acc;
    acc.x = aA.x + aB.x + __uint_as_float(ps.x << 16);
    acc.y = aA.y + aB.y + __uint_as_float(ps.x & 0xFFFF0000u);
    acc.z = aA.z + aB.z + __uint_as_float(ps.y << 16);
    acc.w = aA.w + aB.w + __uint_as_float(ps.y & 0xFFFF0000u);
    float d1 = dinv1[nv];
    float4 bb = ((const float4*)b1s[v])[l];
    float4 h;
    h.x = fmaxf(fmaf(d1, acc.x, bb.x), 0.f);
    h.y = fmaxf(fmaf(d1, acc.y, bb.y), 0.f);
    h.z = fmaxf(fmaf(d1, acc.z, bb.z), 0.f);
    h.w = fmaxf(fmaf(d1, acc.w, bb.w), 0.f);
    fs.x += h.x; fs.y += h.y; fs.z += h.z; fs.w += h.w;
    float4 ww = ((const float4*)W2s[v])[l];
    float p = h.x * ww.x + h.y * ww.y + h.z * ww.z + h.w * ww.w;
    p += __shfl_xor(p, 1, 16);
    p += __shfl_xor(p, 2, 16);
    p += __shfl_xor(p, 4, 16);
    p += __shfl_xor(p, 8, 16);
    if (l == 0) g[nv] = dinv2[nv] * p;
  }
  ((float4*)(outf + (size_t)n * NH))[l] = fs;
}

// ---------------- conv2: LDS-staged g gather (R4) ---------------------------
// Old conv2 = 2.4M random 4B g-gathers = one 64B L2 sector-request per edge,
// capped by the same ~55 G req/s path as conv1 (est ~40us). New: per-view g
// (200KB) split in two 100KB src-halves; each block stages one half into LDS
// and processes its dst-node share against that half's csr segment. Partial
// sums combined in k_cmb (deterministic, no atomics).
__global__ __launch_bounds__(512) void k_conv2(
    const uint* __restrict__ csr, const int* __restrict__ cnt,
    const int* __restrict__ cntA, const float* __restrict__ g,
    float* __restrict__ gpart, int N, int H) {
  __shared__ float lg[25088];  // 100.4 KB (holds H=25000 floats)
  int bx = blockIdx.x;
  int v = bx / (2 * C2K);
  int rem = bx - v * 2 * C2K;
  int half = rem / C2K;
  int k = rem - half * C2K;
  int vN = v * N;
  int base = half * H;
  int hn = min(H, N - base);
  const float* __restrict__ gsrc = g + vN + base;
  int hn4 = hn >> 2;
  const float4* __restrict__ gs4 = (const float4*)gsrc;
  float4* __restrict__ lg4 = (float4*)lg;
  for (int i = threadIdx.x; i < hn4; i += 512) lg4[i] = gs4[i];
  for (int i = hn4 * 4 + threadIdx.x; i < hn; i += 512) lg[i] = gsrc[i];
  __syncthreads();
  int l = threadIdx.x & 15;
  int grp = (threadIdx.x >> 4) + k * 32;   // 32 groups/block, C2K*32 total
  float* __restrict__ out = gpart + (size_t)half * 3 * N + vN;
  for (int n = grp; n < N; n += C2K * 32) {
    int nv = vN + n;
    const uint* __restrict__ row = csr + (size_t)nv * CAP;
    int a = cntA[nv];
    int d = cnt[nv];
    int s0 = half ? a : 0;
    int s1 = half ? d : a;
    float acc = 0.f;
    for (int i = s0 + l; i < s1; i += 16)
      acc += lg[(row[i] & 0xFFFFu) - base];
#pragma unroll
    for (int off = 1; off < 16; off <<= 1) acc += __shfl_xor(acc, off, 16);
    if (l == 0) out[n] = acc;
  }
}

// ---------------- combine: outx = sum_v dinv2*(pA+pB+g_self) + b2 ----------
__global__ __launch_bounds__(256) void k_cmb(
    const float* __restrict__ gpart, const float* __restrict__ g,
    const float* __restrict__ dinv2,
    const float* __restrict__ b20, const float* __restrict__ b21, const float* __restrict__ b22,
    float* __restrict__ outx, int N) {
  int n = blockIdx.x * 256 + threadIdx.x;
  if (n >= N) return;
  int n3 = 3 * N;
  float tot = 0.f;
#pragma unroll
  for (int v = 0; v < 3; v++) {
    int nv = v * N + n;
    tot += dinv2[nv] * (gpart[nv] + gpart[n3 + nv] + g[nv]);
  }
  outx[n] = tot + b20[0] + b21[0] + b22[0];
}

extern "C" void kernel_launch(void* const* d_in, const int* in_sizes, int n_in,
                              void* d_out, int out_size, void* d_ws, size_t ws_size,
                              hipStream_t stream) {
  const float* x   = (const float*)d_in[0];
  const int*   ei0 = (const int*)d_in[1];
  const int*   ei1 = (const int*)d_in[2];
  const int*   ei2 = (const int*)d_in[3];
  const float* ew0 = (const float*)d_in[4];
  const float* ew1 = (const float*)d_in[5];
  const float* ew2 = (const float*)d_in[6];
  const float* W10 = (const float*)d_in[7];
  const float* b10 = (const float*)d_in[8];
  const float* W20 = (const float*)d_in[9];
  const float* b20 = (const float*)d_in[10];
  const float* W11 = (const float*)d_in[11];
  const float* b11 = (const float*)d_in[12];
  const float* W21 = (const float*)d_in[13];
  const float* b21 = (const float*)d_in[14];
  const float* W12 = (const float*)d_in[15];
  const float* b12 = (const float*)d_in[16];
  const float* W22 = (const float*)d_in[17];
  const float* b22 = (const float*)d_in[18];

  const int N = in_sizes[0] / FIN;  // 50000
  const int E = in_sizes[1] / 2;    // 800000
  const int n3 = 3 * N;
  const int H = (N + 1) / 2;        // src-half split point (25000)

  char* p = (char*)d_ws;
  auto alloc = [&](size_t bytes) -> char* {
    char* r = p;
    p += (bytes + 255) & ~(size_t)255;
    return r;
  };
  // bbuf (pass1/2) and xwb (gemm1/conv1) are disjoint in time -> alias
  size_t xwb_bytes  = (size_t)n3 * 32 * sizeof(uint);               // 19.2 MB
  size_t bbuf_bytes = (size_t)3 * NBKT * BCAP * sizeof(uint2);      // 21.7 MB
  char*  shared_rgn = alloc(xwb_bytes > bbuf_bytes ? xwb_bytes : bbuf_bytes);
  uint*  xwb   = (uint*) shared_rgn;
  uint2* bbuf  = (uint2*)shared_rgn;
  uint*  csr   = (uint*) alloc((size_t)n3 * CAP * sizeof(uint));    // 38.4 MB
  uint*  wsw   = (uint*) alloc((size_t)3 * 8192 * sizeof(uint));    // 98 KB
  int*   bcnt  = (int*)  alloc((size_t)3 * NBKT * sizeof(int));
  int*   cnt   = (int*)  alloc((size_t)n3 * sizeof(int));
  int*   cntA  = (int*)  alloc((size_t)n3 * sizeof(int));
  float* dinv1 = (float*)alloc((size_t)n3 * sizeof(float));
  float* dinv2 = (float*)alloc((size_t)n3 * sizeof(float));
  float* g     = (float*)alloc((size_t)n3 * sizeof(float));
  float* gpart = (float*)alloc((size_t)2 * n3 * sizeof(float));     // 1.2 MB
  (void)ws_size;

  float* outx = (float*)d_out;        // [N]
  float* outf = (float*)d_out + N;    // [N][64]

  k_wprep<<<dim3(3), 256, 0, stream>>>(W10, W11, W12, wsw, bcnt);
  k_p1<<<dim3((E + EPB - 1) / EPB, 3), 256, 0, stream>>>(ei0, ei1, ei2,
                                                         ew0, ew1, ew2, bcnt, bbuf, E);
  k_p2<<<dim3(NBKT, 3), 256, 0, stream>>>(bcnt, bbuf, cnt, cntA, csr, dinv1, dinv2, N, H);
  k_gemm1m<<<dim3((N + 63) / 64), 256, 0, stream>>>(x, wsw, dinv1, xwb, N);
  k_conv1<<<dim3((N * 16 + 255) / 256), 256, 0, stream>>>(
      xwb, csr, cnt, dinv1, dinv2, b10, b11, b12, W20, W21, W22, outf, g, N);
  k_conv2<<<dim3(3 * 2 * C2K), 512, 0, stream>>>(csr, cnt, cntA, g, gpart, N, H);
  k_cmb<<<dim3((N + 255) / 256), 256, 0, stream>>>(gpart, g, dinv2,
                                                   b20, b21, b22, outx, N);
}

// Round 5
// 283.277 us; speedup vs baseline: 1.1101x; 1.1101x over previous
//
#include <hip/hip_runtime.h>
#include <hip/hip_fp16.h>
#include <stdint.h>
#include <stddef.h>

#define FIN 256
#define NH  64
#define CAP 64     // max degree: E/N=16 avg Poisson, P(deg>64) ~ 1e-19
#define NBKT 196   // ceil(50000/256) dst buckets of 256 nodes
#define BCAP 4608  // bucket region capacity: mean 4082, sd 64, +8 sigma
#define LBUF 32    // LDS staging records per bucket
#define LSTR 33    // padded LDS stride (odd -> banks spread across buckets)
#define ROUND 4096 // edges staged per block-synchronous round
#define EPB 4096   // edges per block in pass 1 (= 1 round -> 588 blocks)

typedef unsigned int uint;
typedef __attribute__((ext_vector_type(8))) short bf16x8;  // MFMA A/B frag (4 VGPRs)
typedef __attribute__((ext_vector_type(4))) float f32x4;   // MFMA C/D frag

union ABfrag { uint u[4]; bf16x8 v; };

// pack two fp32 -> bf16 pair (RNE), low = first element
__device__ __forceinline__ uint pack_bf16x2(float a, float b) {
  uint ua = __float_as_uint(a);
  uint ub = __float_as_uint(b);
  uint ra = (ua + 0x7FFFu + ((ua >> 16) & 1u)) >> 16;
  uint rb = (ub + 0x7FFFu + ((ub >> 16) & 1u)) & 0xFFFF0000u;
  return ra | rb;
}

__device__ __forceinline__ float rec_w(uint r) {
  return __half2float(__ushort_as_half((unsigned short)(r >> 16)));
}

// ---------------- W1 -> MFMA B-frag swizzle + zero bucket counters ----------
// wsw[v][ks(8)][nt(4)][lane(64)][4 uints]; elem j = W1[ks*32+(lane>>4)*8+j][nt*16+(lane&15)]
__global__ __launch_bounds__(256) void k_wprep(
    const float* __restrict__ W10, const float* __restrict__ W11, const float* __restrict__ W12,
    uint* __restrict__ wsw, int* __restrict__ bcnt) {
  int v = blockIdx.x;
  const float* __restrict__ W = v == 0 ? W10 : (v == 1 ? W11 : W12);
  uint4* __restrict__ o = (uint4*)(wsw + v * 8192);
  for (int t = threadIdx.x; t < 2048; t += 256) {
    int lane = t & 63;
    int nt = (t >> 6) & 3;
    int ks = t >> 8;
    int kb = ks * 32 + (lane >> 4) * 8;
    int col = nt * 16 + (lane & 15);
    uint4 r;
    r.x = pack_bf16x2(W[(kb + 0) * NH + col], W[(kb + 1) * NH + col]);
    r.y = pack_bf16x2(W[(kb + 2) * NH + col], W[(kb + 3) * NH + col]);
    r.z = pack_bf16x2(W[(kb + 4) * NH + col], W[(kb + 5) * NH + col]);
    r.w = pack_bf16x2(W[(kb + 6) * NH + col], W[(kb + 7) * NH + col]);
    o[t] = r;
  }
  if (threadIdx.x < NBKT) bcnt[v * NBKT + threadIdx.x] = 0;
}

// ---------------- pass 1: bucket edges by dst>>8 via LDS staging ------------
// stage: 1 edge/thread; flush: PER-THREAD (parallel contended atomics --
// wave-serial flush with returning atomics was a 200us regression in R9)
__global__ __launch_bounds__(256) void k_p1(
    const int* __restrict__ ei0, const int* __restrict__ ei1, const int* __restrict__ ei2,
    const float* __restrict__ ew0, const float* __restrict__ ew1, const float* __restrict__ ew2,
    int* __restrict__ bcnt, uint2* __restrict__ bbuf, int E) {
  int v = blockIdx.y;
  const int*   ei = v == 0 ? ei0 : (v == 1 ? ei1 : ei2);
  const float* ew = v == 0 ? ew0 : (v == 1 ? ew1 : ew2);
  int* __restrict__ bc = bcnt + v * NBKT;
  uint2* __restrict__ bb = bbuf + (size_t)v * NBKT * BCAP;
  __shared__ uint2 buf[NBKT * LSTR];   // 51.7 KB -> 3 blocks/CU
  __shared__ int ticket[NBKT];
  int tid = threadIdx.x;
  int base = blockIdx.x * EPB;
  int end = min(base + EPB, E);
  for (int rbase = base; rbase < end; rbase += ROUND) {
    for (int b = tid; b < NBKT; b += 256) ticket[b] = 0;
    __syncthreads();
    for (int i = 0; i < ROUND; i += 256) {
      int e = rbase + i + tid;
      if (e < end) {
        int s = ei[e];
        int d = ei[E + e];
        float w = ew[e];
        int bkt = d >> 8;
        uint2 rec;
        rec.x = (uint)s | ((uint)(d & 255) << 16);
        rec.y = __float_as_uint(w);
        int t = atomicAdd(&ticket[bkt], 1);
        if (t < LBUF) {
          buf[bkt * LSTR + t] = rec;
        } else {
          int gp = atomicAdd(&bc[bkt], 1);
          if (gp < BCAP) bb[(size_t)bkt * BCAP + gp] = rec;
        }
      }
    }
    __syncthreads();
    // flush: one thread per bucket -> all global atomics issue concurrently
    for (int b = tid; b < NBKT; b += 256) {
      int c = min(ticket[b], LBUF);
      if (c > 0) {
        int gbase = atomicAdd(&bc[b], c);
        for (int j = 0; j < c; j++) {
          int gp = gbase + j;
          if (gp < BCAP) bb[(size_t)b * BCAP + gp] = buf[b * LSTR + j];
        }
      }
    }
    __syncthreads();
  }
}

// ---------------- pass 2: bucket -> CSR rows (8-padded) + cnt + dinv --------
// Pad records are src=0, w=+0 -> inert in conv1 (0*finite=0), skipped by conv2.
__global__ __launch_bounds__(256) void k_p2(
    const int* __restrict__ bcnt, const uint2* __restrict__ bbuf,
    int* __restrict__ cnt, uint* __restrict__ csr,
    float* __restrict__ dinv1, float* __restrict__ dinv2, int N) {
  int bkt = blockIdx.x;
  int v = blockIdx.y;
  int tid = threadIdx.x;
  __shared__ int lcnt[256];
  __shared__ float lsum[256];
  lcnt[tid] = 0;
  lsum[tid] = 0.f;
  __syncthreads();
  int m = min(bcnt[v * NBKT + bkt], BCAP);
  const uint2* __restrict__ bb = bbuf + ((size_t)v * NBKT + bkt) * BCAP;
  int nb = bkt << 8;
  int vN = v * N;
  for (int i = tid; i < m; i += 256) {
    uint2 rec = bb[i];
    int src = rec.x & 0xFFFFu;
    int dl = (rec.x >> 16) & 0xFFu;
    float w = __uint_as_float(rec.y);
    int pos = atomicAdd(&lcnt[dl], 1);
    uint r4 = (uint)src | ((uint)__half_as_ushort(__float2half_rn(w)) << 16);
    if (pos < CAP) csr[((size_t)(vN + nb + dl)) * CAP + pos] = r4;
    atomicAdd(&lsum[dl], w);
  }
  __syncthreads();
  int node = nb + tid;
  if (node < N) {
    int deg = min(lcnt[tid], CAP);
    int dpad = min((deg + 7) & ~7, CAP);
    uint* __restrict__ row = csr + (size_t)(vN + node) * CAP;
    for (int i = deg; i < dpad; i++) row[i] = 0u;  // src=0, w=+0 (inert in conv1)
    cnt[vN + node] = deg;
    dinv1[vN + node] = rsqrtf(1.0f + lsum[tid]);
    dinv2[vN + node] = rsqrtf((float)(deg + 1));
  }
}

// ---------------- GEMM1 via MFMA, 3 branches fused (x read once) ------------
__global__ __launch_bounds__(256) void k_gemm1m(
    const float* __restrict__ x, const uint* __restrict__ wsw,
    const float* __restrict__ dinv1, uint* __restrict__ xwb, int N) {
  __shared__ float sc_all[4 * 16 * 64];  // 16 KB epilogue scratch (per-wave 4 KB)
  int wave = threadIdx.x >> 6, lane = threadIdx.x & 63;
  int n0 = blockIdx.x * 64 + wave * 16;
  int m = lane & 15, kq = lane >> 4;  // A: node m, k-group kq
  int arow = min(n0 + m, N - 1);
  const float* __restrict__ xr = x + (size_t)arow * FIN + kq * 8;
  ABfrag af[8];
#pragma unroll
  for (int ks = 0; ks < 8; ks++) {
    float4 a0 = *(const float4*)(xr + ks * 32);
    float4 a1 = *(const float4*)(xr + ks * 32 + 4);
    af[ks].u[0] = pack_bf16x2(a0.x, a0.y);
    af[ks].u[1] = pack_bf16x2(a0.z, a0.w);
    af[ks].u[2] = pack_bf16x2(a1.x, a1.y);
    af[ks].u[3] = pack_bf16x2(a1.z, a1.w);
  }
  float* sc = &sc_all[wave * 1024];  // 16x64 fp32 per wave
  int row2 = lane >> 2, cg = lane & 3;
  int node = n0 + row2;
#pragma unroll
  for (int v = 0; v < 3; v++) {
    int vN = v * N;
    f32x4 acc[4];
#pragma unroll
    for (int nt = 0; nt < 4; nt++) acc[nt] = (f32x4){0.f, 0.f, 0.f, 0.f};
    const uint* __restrict__ wv = wsw + v * 8192;
#pragma unroll
    for (int ks = 0; ks < 8; ks++) {
#pragma unroll
      for (int nt = 0; nt < 4; nt++) {
        ABfrag b;
        *(uint4*)b.u = *(const uint4*)&wv[(ks * 4 + nt) * 256 + lane * 4];
        acc[nt] = __builtin_amdgcn_mfma_f32_16x16x32_bf16(af[ks].v, b.v, acc[nt], 0, 0, 0);
      }
    }
    __syncthreads();  // epilogue scratch reuse boundary (prev v's reads done)
#pragma unroll
    for (int reg = 0; reg < 4; reg++) {
      int row = kq * 4 + reg;            // C/D: row=(lane>>4)*4+reg, col=lane&15
      float d1 = dinv1[vN + min(n0 + row, N - 1)];
#pragma unroll
      for (int nt = 0; nt < 4; nt++)
        sc[row * 64 + nt * 16 + m] = acc[nt][reg] * d1;
    }
    __syncthreads();
    const float4* sr = (const float4*)&sc[row2 * 64 + cg * 16];
    float4 c0 = sr[0], c1 = sr[1], c2 = sr[2], c3 = sr[3];
    uint4 o0, o1;
    o0.x = pack_bf16x2(c0.x, c0.y); o0.y = pack_bf16x2(c0.z, c0.w);
    o0.z = pack_bf16x2(c1.x, c1.y); o0.w = pack_bf16x2(c1.z, c1.w);
    o1.x = pack_bf16x2(c2.x, c2.y); o1.y = pack_bf16x2(c2.z, c2.w);
    o1.z = pack_bf16x2(c3.x, c3.y); o1.w = pack_bf16x2(c3.z, c3.w);
    if (node < N) {
      uint4* __restrict__ dst = (uint4*)(xwb + ((size_t)vN + node) * 32 + cg * 8);
      dst[0] = o0;
      dst[1] = o1;
    }
  }
}

// ---------------- conv1 pull: 16 lanes/node, full-line gathers --------------
// R12 analysis: FETCH ~130MB is per-XCD compulsory duplication (8 XCDs x 3
// views x 0.86 coverage x 50k x 128B). Rate ~55 G line-req/s, VALU 34%,
// occ 46% -> outstanding-miss-capacity x miss-latency bound (~31/CU).
// R13: dispatched in TWO half-node launches (n0..n1) purely so the ~27us
// halves drop below the hidden kernels in rocprof's top-5 -- visibility for
// the 222us of pipeline that is NOT conv1. Same total work.
#define EDG(r, a)                                                  \
  {                                                                \
    uint2 pp = *(const uint2*)(xv + (((r) & 0xFFFFu) << 7) + so);  \
    float ww = rec_w(r);                                           \
    a.x = fmaf(ww, __uint_as_float(pp.x << 16), a.x);              \
    a.y = fmaf(ww, __uint_as_float(pp.x & 0xFFFF0000u), a.y);      \
    a.z = fmaf(ww, __uint_as_float(pp.y << 16), a.z);              \
    a.w = fmaf(ww, __uint_as_float(pp.y & 0xFFFF0000u), a.w);      \
  }

__global__ __launch_bounds__(256) void k_conv1(
    const uint* __restrict__ xwb, const uint* __restrict__ csr,
    const int* __restrict__ cnt,
    const float* __restrict__ dinv1, const float* __restrict__ dinv2,
    const float* __restrict__ b10, const float* __restrict__ b11, const float* __restrict__ b12,
    const float* __restrict__ W20, const float* __restrict__ W21, const float* __restrict__ W22,
    float* __restrict__ outf, float* __restrict__ g, int N, int nbase, int nend) {
  int gt = blockIdx.x * 256 + threadIdx.x;
  int l = gt & 15;
  int n = nbase + (gt >> 4);
  if (n >= nend) return;
  int so = l << 3;  // lane's byte offset (8B) within the 128B xwb row
  const float* b1s[3] = {b10, b11, b12};
  const float* W2s[3] = {W20, W21, W22};
  int c0 = cnt[n], c1 = cnt[N + n], c2 = cnt[2 * N + n];  // hoisted
  float4 fs = {0.f, 0.f, 0.f, 0.f};
#pragma unroll
  for (int v = 0; v < 3; v++) {
    int vN = v * N;
    int nv = vN + n;
    const char* __restrict__ xv = (const char*)xwb + (size_t)vN * 128;  // SGPR base
    const uint* __restrict__ row = csr + (size_t)nv * CAP;  // 256B-aligned
    int deg = v == 0 ? c0 : (v == 1 ? c1 : c2);
    int dpad = (deg + 7) & ~7;
    float4 aA = {0.f, 0.f, 0.f, 0.f}, aB = {0.f, 0.f, 0.f, 0.f};
    for (int i = 0; i < dpad; i += 8) {
      uint4 ra = *(const uint4*)(row + i);      // broadcast within 16-lane group
      uint4 rb = *(const uint4*)(row + i + 4);
      EDG(ra.x, aA); EDG(ra.y, aB);
      EDG(ra.z, aA); EDG(ra.w, aB);
      EDG(rb.x, aA); EDG(rb.y, aB);
      EDG(rb.z, aA); EDG(rb.w, aB);
    }
    uint2 ps = *(const uint2*)(xv + (((uint)n) << 7) + so);  // self loop
    float4 acc;
    acc.x = aA.x + aB.x + __uint_as_float(ps.x << 16);
    acc.y = aA.y + aB.y + __uint_as_float(ps.x & 0xFFFF0000u);
    acc.z = aA.z + aB.z + __uint_as_float(ps.y << 16);
    acc.w = aA.w + aB.w + __uint_as_float(ps.y & 0xFFFF0000u);
    float d1 = dinv1[nv];
    float4 bb = ((const float4*)b1s[v])[l];
    float4 h;
    h.x = fmaxf(fmaf(d1, acc.x, bb.x), 0.f);
    h.y = fmaxf(fmaf(d1, acc.y, bb.y), 0.f);
    h.z = fmaxf(fmaf(d1, acc.z, bb.z), 0.f);
    h.w = fmaxf(fmaf(d1, acc.w, bb.w), 0.f);
    fs.x += h.x; fs.y += h.y; fs.z += h.z; fs.w += h.w;
    float4 ww = ((const float4*)W2s[v])[l];
    float p = h.x * ww.x + h.y * ww.y + h.z * ww.z + h.w * ww.w;
    p += __shfl_xor(p, 1, 16);
    p += __shfl_xor(p, 2, 16);
    p += __shfl_xor(p, 4, 16);
    p += __shfl_xor(p, 8, 16);
    if (l == 0) g[nv] = dinv2[nv] * p;
  }
  ((float4*)(outf + (size_t)n * NH))[l] = fs;
}

// ---------------- conv2 pull: 16 lanes/node (true deg — ignores pads) -------
__global__ __launch_bounds__(256) void k_conv2(
    const uint* __restrict__ csr, const int* __restrict__ cnt,
    const float* __restrict__ dinv2, const float* __restrict__ g,
    const float* __restrict__ b20, const float* __restrict__ b21, const float* __restrict__ b22,
    float* __restrict__ outx, int N) {
  int gt = blockIdx.x * 256 + threadIdx.x;
  int l = gt & 15;
  int n = gt >> 4;
  if (n >= N) return;
  float tot = 0.f;
#pragma unroll
  for (int v = 0; v < 3; v++) {
    int vN = v * N;
    int nv = vN + n;
    const uint* __restrict__ row = csr + (size_t)nv * CAP;
    int deg = cnt[nv];
    float acc = 0.f;
    for (int i = l; i < deg; i += 16) acc += g[vN + (row[i] & 0xFFFFu)];
#pragma unroll
    for (int off = 1; off < 16; off <<= 1) acc += __shfl_xor(acc, off, 16);
    tot += dinv2[nv] * (acc + g[nv]);
  }
  if (l == 0) outx[n] = tot + b20[0] + b21[0] + b22[0];
}

extern "C" void kernel_launch(void* const* d_in, const int* in_sizes, int n_in,
                              void* d_out, int out_size, void* d_ws, size_t ws_size,
                              hipStream_t stream) {
  const float* x   = (const float*)d_in[0];
  const int*   ei0 = (const int*)d_in[1];
  const int*   ei1 = (const int*)d_in[2];
  const int*   ei2 = (const int*)d_in[3];
  const float* ew0 = (const float*)d_in[4];
  const float* ew1 = (const float*)d_in[5];
  const float* ew2 = (const float*)d_in[6];
  const float* W10 = (const float*)d_in[7];
  const float* b10 = (const float*)d_in[8];
  const float* W20 = (const float*)d_in[9];
  const float* b20 = (const float*)d_in[10];
  const float* W11 = (const float*)d_in[11];
  const float* b11 = (const float*)d_in[12];
  const float* W21 = (const float*)d_in[13];
  const float* b21 = (const float*)d_in[14];
  const float* W12 = (const float*)d_in[15];
  const float* b12 = (const float*)d_in[16];
  const float* W22 = (const float*)d_in[17];
  const float* b22 = (const float*)d_in[18];

  const int N = in_sizes[0] / FIN;  // 50000
  const int E = in_sizes[1] / 2;    // 800000
  const int n3 = 3 * N;

  char* p = (char*)d_ws;
  auto alloc = [&](size_t bytes) -> char* {
    char* r = p;
    p += (bytes + 255) & ~(size_t)255;
    return r;
  };
  // bbuf (pass1/2) and xwb (gemm1/conv1) are disjoint in time -> alias
  size_t xwb_bytes  = (size_t)n3 * 32 * sizeof(uint);               // 19.2 MB
  size_t bbuf_bytes = (size_t)3 * NBKT * BCAP * sizeof(uint2);      // 21.7 MB
  char*  shared_rgn = alloc(xwb_bytes > bbuf_bytes ? xwb_bytes : bbuf_bytes);
  uint*  xwb   = (uint*) shared_rgn;
  uint2* bbuf  = (uint2*)shared_rgn;
  uint*  csr   = (uint*) alloc((size_t)n3 * CAP * sizeof(uint));    // 38.4 MB
  uint*  wsw   = (uint*) alloc((size_t)3 * 8192 * sizeof(uint));    // 98 KB
  int*   bcnt  = (int*)  alloc((size_t)3 * NBKT * sizeof(int));
  int*   cnt   = (int*)  alloc((size_t)n3 * sizeof(int));
  float* dinv1 = (float*)alloc((size_t)n3 * sizeof(float));
  float* dinv2 = (float*)alloc((size_t)n3 * sizeof(float));
  float* g     = (float*)alloc((size_t)n3 * sizeof(float));
  (void)ws_size;

  float* outx = (float*)d_out;        // [N]
  float* outf = (float*)d_out + N;    // [N][64]

  const int NHALF = N / 2;  // 25000

  k_wprep<<<dim3(3), 256, 0, stream>>>(W10, W11, W12, wsw, bcnt);
  k_p1<<<dim3((E + EPB - 1) / EPB, 3), 256, 0, stream>>>(ei0, ei1, ei2,
                                                         ew0, ew1, ew2, bcnt, bbuf, E);
  k_p2<<<dim3(NBKT, 3), 256, 0, stream>>>(bcnt, bbuf, cnt, csr, dinv1, dinv2, N);
  k_gemm1m<<<dim3((N + 63) / 64), 256, 0, stream>>>(x, wsw, dinv1, xwb, N);
  k_conv1<<<dim3((NHALF * 16 + 255) / 256), 256, 0, stream>>>(
      xwb, csr, cnt, dinv1, dinv2, b10, b11, b12, W20, W21, W22, outf, g, N, 0, NHALF);
  k_conv1<<<dim3(((N - NHALF) * 16 + 255) / 256), 256, 0, stream>>>(
      xwb, csr, cnt, dinv1, dinv2, b10, b11, b12, W20, W21, W22, outf, g, N, NHALF, N);
  k_conv2<<<dim3((N * 16 + 255) / 256), 256, 0, stream>>>(csr, cnt, dinv2, g,
                                                          b20, b21, b22, outx, N);
}